// Round 4
// baseline (621.612 us; speedup 1.0000x reference)
//
#include <hip/hip_runtime.h>
#include <math.h>
#include <stdint.h>

// Problem constants (deterministic from setup_inputs)
#define NB 32
#define NQ 300
#define ND 256
#define NH 8
#define HD 32
#define NL 4
#define NP 4
#define V_TOT 8500           // 6400+1600+400+100
#define BQ_TOT (NB*NQ)       // 9600
#define MVAL (NB*V_TOT)      // 272000
#define NOA 384              // fused off(256)+attn(128) cols

typedef short v8s __attribute__((ext_vector_type(8)));
typedef float v4f __attribute__((ext_vector_type(4)));

#define AS1 __attribute__((address_space(1)))
#define AS3 __attribute__((address_space(3)))

__device__ __forceinline__ void copy16_async(const void* g, void* l) {
#if __has_builtin(__builtin_amdgcn_global_load_lds)
    __builtin_amdgcn_global_load_lds((const AS1 unsigned int*)g,
                                     (AS3 unsigned int*)l, 16, 0, 0);
#else
    *(uint4*)l = *(const uint4*)g;
#endif
}

__device__ __forceinline__ unsigned short f2bf_rne(float x) {
    unsigned u = __float_as_uint(x);
    u += 0x7fffu + ((u >> 16) & 1u);
    return (unsigned short)(u >> 16);
}
__device__ __forceinline__ float bf2f(unsigned short b) {
    return __uint_as_float(((unsigned)b) << 16);
}

// Swizzled flat position of element (n,k) in a prepped [N][256] bf16 array.
// Within each 32-k tile the 4 octets are XOR-permuted by ((n>>1)&3) so
// unpadded LDS fragment reads are only 2-way conflicted (free per m136).
__device__ __forceinline__ int swz_pos(int n, int k) {
    const int base = k & ~31;
    const int o = (k >> 3) & 3;
    const int op = o ^ ((n >> 1) & 3);
    return n * 256 + base + (op << 3) + (k & 7);
}

// ---------------------------------------------------------------------------
// Prep: transpose + hi/lo-split (RNE) all three weight matrices into
// n-major swizzled bf16; concat biases for the fused off/attn projection.
// ---------------------------------------------------------------------------
__global__ __launch_bounds__(256) void prep_weights(
    const float* __restrict__ W_val, const float* __restrict__ W_off,
    const float* __restrict__ W_attn, const float* __restrict__ W_out,
    const float* __restrict__ b_off, const float* __restrict__ b_attn,
    unsigned short* __restrict__ Bval_h, unsigned short* __restrict__ Bval_l,
    unsigned short* __restrict__ Boa_h,  unsigned short* __restrict__ Boa_l,
    unsigned short* __restrict__ Bout_h, unsigned short* __restrict__ Bout_l,
    float* __restrict__ b_oa)
{
    const int t = blockIdx.x * 256 + threadIdx.x;
    if (t < 65536) {
        const int n = t >> 8, k = t & 255;
        const float x = W_val[k * 256 + n];
        const unsigned short hi = f2bf_rne(x);
        const unsigned short lo = f2bf_rne(x - bf2f(hi));
        const int p = swz_pos(n, k);
        Bval_h[p] = hi; Bval_l[p] = lo;
    } else if (t < 65536 + 98304) {
        const int t2 = t - 65536;
        const int n = t2 >> 8, k = t2 & 255;
        const float x = (n < 256) ? W_off[k * 256 + n] : W_attn[k * 128 + (n - 256)];
        const unsigned short hi = f2bf_rne(x);
        const unsigned short lo = f2bf_rne(x - bf2f(hi));
        const int p = swz_pos(n, k);
        Boa_h[p] = hi; Boa_l[p] = lo;
    } else if (t < 229376) {
        const int t3 = t - 163840;
        const int n = t3 >> 8, k = t3 & 255;
        const float x = W_out[k * 256 + n];
        const unsigned short hi = f2bf_rne(x);
        const unsigned short lo = f2bf_rne(x - bf2f(hi));
        const int p = swz_pos(n, k);
        Bout_h[p] = hi; Bout_l[p] = lo;
    } else {
        const int t4 = t - 229376;
        if (t4 < NOA) b_oa[t4] = (t4 < 256) ? b_off[t4] : b_attn[t4 - 256];
    }
}

// ---------------------------------------------------------------------------
// Specialized val GEMM: C = value(Mx256) @ W_val(256x256) + b_val, bf16-split
// 3-product MFMA. BM=128, BN=256 (full width -> A is loaded & split ONCE),
// BK=32. 4 waves, each a 64x128 sub-tile (4 m-tiles x 8 n-tiles).
// Output bf16 val layout: C[((b*NH+h)*V_TOT+v)*HD+dh], row=(b,v), col=(h,dh).
// ---------------------------------------------------------------------------
__global__ __launch_bounds__(256) void gemm_val256(
    const float* __restrict__ A,              // value [M x 256]
    const unsigned short* __restrict__ Bh,    // [256 n][256 k] bf16 swizzled
    const unsigned short* __restrict__ Bl,
    const float* __restrict__ bias,
    unsigned short* __restrict__ Cb)
{
    __shared__ unsigned short Ah[128][40];    // padded: 80B rows -> 2-way only
    __shared__ unsigned short Al[128][40];
    __shared__ unsigned short Bs[2][256][32]; // unpadded, swizzled octets

    const int tid  = threadIdx.x;
    const int row0 = blockIdx.x * 128;
    const int wave = tid >> 6;
    const int lane = tid & 63;
    const int wm   = (wave >> 1) * 64;        // 0 or 64
    const int wn   = (wave & 1) * 128;        // 0 or 128
    const int m16  = lane & 15;
    const int quad = lane >> 4;

    v4f acc[4][8] = {};

    for (int k0 = 0; k0 < 256; k0 += 32) {
        // ---- A: 16 f32 per thread, truncation hi/lo split in registers ----
        unsigned hpk[2][4], lpk[2][4];
        int rr[2], oo[2];
#pragma unroll
        for (int i = 0; i < 2; ++i) {
            const int idx = tid + i * 256;        // 0..511
            const int r   = idx >> 2;             // 0..127
            const int oct = (idx & 3) << 3;       // 0,8,16,24 (elements)
            rr[i] = r; oo[i] = oct;
            const float4 f0 = *(const float4*)(A + (size_t)(row0 + r) * 256 + k0 + oct);
            const float4 f1 = *(const float4*)(A + (size_t)(row0 + r) * 256 + k0 + oct + 4);
            const float fe[8] = {f0.x, f0.y, f0.z, f0.w, f1.x, f1.y, f1.z, f1.w};
#pragma unroll
            for (int e = 0; e < 4; ++e) {
                const unsigned u0 = __float_as_uint(fe[2*e]);
                const unsigned u1 = __float_as_uint(fe[2*e+1]);
                hpk[i][e] = (u0 >> 16) | (u1 & 0xffff0000u);
                const float l0 = fe[2*e]   - __uint_as_float(u0 & 0xffff0000u);
                const float l1 = fe[2*e+1] - __uint_as_float(u1 & 0xffff0000u);
                lpk[i][e] = (__float_as_uint(l0) >> 16) | (__float_as_uint(l1) & 0xffff0000u);
            }
        }

        __syncthreads();   // previous iteration's LDS readers done

        // ---- B: async global->LDS, 256n x 32k hi+lo (16 KB each) ----
#pragma unroll
        for (int p = 0; p < 4; ++p) {
            const int linear = p * 4096 + tid * 16;     // bytes, lane-contiguous
            const int n   = linear >> 6;
            const int off = linear & 63;
            copy16_async((const char*)Bh + ((size_t)n * 256 + k0) * 2 + off,
                         (char*)&Bs[0][0][0] + linear);
            copy16_async((const char*)Bl + ((size_t)n * 256 + k0) * 2 + off,
                         (char*)&Bs[1][0][0] + linear);
        }

        // ---- A: write packed hi/lo to LDS (b128) ----
#pragma unroll
        for (int i = 0; i < 2; ++i) {
            *(uint4*)&Ah[rr[i]][oo[i]] = make_uint4(hpk[i][0], hpk[i][1], hpk[i][2], hpk[i][3]);
            *(uint4*)&Al[rr[i]][oo[i]] = make_uint4(lpk[i][0], lpk[i][1], lpk[i][2], lpk[i][3]);
        }

        __syncthreads();   // drains vmcnt (async B) + lgkm (A writes)

        // ---- A fragments (reused across all 8 n-tiles) ----
        v8s ah[4], al[4];
#pragma unroll
        for (int i = 0; i < 4; ++i) {
            ah[i] = *(v8s*)&Ah[wm + i * 16 + m16][quad * 8];
            al[i] = *(v8s*)&Al[wm + i * 16 + m16][quad * 8];
        }
        // ---- per-j B fragments, 12 MFMAs per 2 ds_read_b128 ----
#pragma unroll
        for (int j = 0; j < 8; ++j) {
            const int n  = wn + j * 16 + m16;
            const int ko = (quad ^ ((n >> 1) & 3)) << 3;
            const v8s bh = *(v8s*)&Bs[0][n][ko];
            const v8s bl = *(v8s*)&Bs[1][n][ko];
#pragma unroll
            for (int i = 0; i < 4; ++i) {
                acc[i][j] = __builtin_amdgcn_mfma_f32_16x16x32_bf16(ah[i], bh, acc[i][j], 0, 0, 0);
                acc[i][j] = __builtin_amdgcn_mfma_f32_16x16x32_bf16(ah[i], bl, acc[i][j], 0, 0, 0);
                acc[i][j] = __builtin_amdgcn_mfma_f32_16x16x32_bf16(al[i], bh, acc[i][j], 0, 0, 0);
            }
        }
    }

    // ---- epilogue: D[row=quad*4+reg][col=lane&15] -> bf16 val layout ----
#pragma unroll
    for (int j = 0; j < 8; ++j) {
        const int cl = wn + j * 16 + m16;            // global col (N=256)
        const float bb = bias[cl];
        const int h  = cl >> 5;
        const int dh = cl & 31;
#pragma unroll
        for (int i = 0; i < 4; ++i)
#pragma unroll
            for (int r = 0; r < 4; ++r) {
                const int R = row0 + wm + i * 16 + quad * 4 + r;
                const unsigned b = (unsigned)R / V_TOT;
                const int v = R - (int)b * V_TOT;
                Cb[(((size_t)(b * NH + h)) * V_TOT + v) * HD + dh] =
                    f2bf_rne(acc[i][j][r] + bb);
            }
    }
}

// ---------------------------------------------------------------------------
// GEMM, f32 A (kept for the oa projection): BM=BN=128, BK=32, f32 out.
// ---------------------------------------------------------------------------
__global__ __launch_bounds__(256) void gemm_a32(
    const float* __restrict__ A,
    const unsigned short* __restrict__ Bh,
    const unsigned short* __restrict__ Bl,
    const float* __restrict__ bias,
    float* __restrict__ Cf, int ldc)
{
    __shared__ unsigned short Ah[128][40];
    __shared__ unsigned short Al[128][40];
    __shared__ unsigned short Bs[2][128][32];

    const int tid  = threadIdx.x;
    const int row0 = blockIdx.x * 128;
    const int col0 = blockIdx.y * 128;
    const int wave = tid >> 6;
    const int lane = tid & 63;
    const int wm   = (wave >> 1) * 64;
    const int wn   = (wave & 1) * 64;
    const int m16  = lane & 15;
    const int quad = lane >> 4;

    v4f acc[4][4] = {};

    for (int k0 = 0; k0 < 256; k0 += 32) {
        unsigned hpk[2][4], lpk[2][4];
        int rr[2], oo[2];
#pragma unroll
        for (int i = 0; i < 2; ++i) {
            const int idx = tid + i * 256;
            const int r   = idx >> 2;
            const int oct = (idx & 3) << 3;
            rr[i] = r; oo[i] = oct;
            const float4 f0 = *(const float4*)(A + (size_t)(row0 + r) * 256 + k0 + oct);
            const float4 f1 = *(const float4*)(A + (size_t)(row0 + r) * 256 + k0 + oct + 4);
            const float fe[8] = {f0.x, f0.y, f0.z, f0.w, f1.x, f1.y, f1.z, f1.w};
#pragma unroll
            for (int e = 0; e < 4; ++e) {
                const unsigned u0 = __float_as_uint(fe[2*e]);
                const unsigned u1 = __float_as_uint(fe[2*e+1]);
                hpk[i][e] = (u0 >> 16) | (u1 & 0xffff0000u);
                const float l0 = fe[2*e]   - __uint_as_float(u0 & 0xffff0000u);
                const float l1 = fe[2*e+1] - __uint_as_float(u1 & 0xffff0000u);
                lpk[i][e] = (__float_as_uint(l0) >> 16) | (__float_as_uint(l1) & 0xffff0000u);
            }
        }

        __syncthreads();

#pragma unroll
        for (int c = 0; c < 2; ++c) {
            const int linear = (wave * 2 + c) * 1024 + lane * 16;
            const int n   = linear >> 6;
            const int off = linear & 63;
            copy16_async((const char*)Bh + ((size_t)(col0 + n) * 256 + k0) * 2 + off,
                         (char*)&Bs[0][0][0] + linear);
            copy16_async((const char*)Bl + ((size_t)(col0 + n) * 256 + k0) * 2 + off,
                         (char*)&Bs[1][0][0] + linear);
        }

#pragma unroll
        for (int i = 0; i < 2; ++i) {
            *(uint4*)&Ah[rr[i]][oo[i]] = make_uint4(hpk[i][0], hpk[i][1], hpk[i][2], hpk[i][3]);
            *(uint4*)&Al[rr[i]][oo[i]] = make_uint4(lpk[i][0], lpk[i][1], lpk[i][2], lpk[i][3]);
        }

        __syncthreads();

        v8s ah[4], al[4], bh[4], bl[4];
#pragma unroll
        for (int i = 0; i < 4; ++i) {
            ah[i] = *(v8s*)&Ah[wm + i * 16 + m16][quad * 8];
            al[i] = *(v8s*)&Al[wm + i * 16 + m16][quad * 8];
            const int n  = wn + i * 16 + m16;
            const int ko = (quad ^ ((n >> 1) & 3)) << 3;
            bh[i] = *(v8s*)&Bs[0][n][ko];
            bl[i] = *(v8s*)&Bs[1][n][ko];
        }
#pragma unroll
        for (int i = 0; i < 4; ++i)
#pragma unroll
            for (int j = 0; j < 4; ++j) {
                acc[i][j] = __builtin_amdgcn_mfma_f32_16x16x32_bf16(ah[i], bh[j], acc[i][j], 0, 0, 0);
                acc[i][j] = __builtin_amdgcn_mfma_f32_16x16x32_bf16(ah[i], bl[j], acc[i][j], 0, 0, 0);
                acc[i][j] = __builtin_amdgcn_mfma_f32_16x16x32_bf16(al[i], bh[j], acc[i][j], 0, 0, 0);
            }
    }

#pragma unroll
    for (int j = 0; j < 4; ++j) {
        const int cl = col0 + wn + j * 16 + m16;
        const float bb = bias[cl];
#pragma unroll
        for (int i = 0; i < 4; ++i)
#pragma unroll
            for (int r = 0; r < 4; ++r) {
                const int R = row0 + wm + i * 16 + quad * 4 + r;
                Cf[(size_t)R * ldc + cl] = acc[i][j][r] + bb;
            }
    }
}

// ---------------------------------------------------------------------------
// GEMM, bf16 A (pre-swizzled rows): out = pre @ W_out + b_out, f32 out.
// ---------------------------------------------------------------------------
__global__ __launch_bounds__(256) void gemm_a16(
    const unsigned short* __restrict__ A,     // [M][256] bf16, swizzled octets
    const unsigned short* __restrict__ Bh,
    const unsigned short* __restrict__ Bl,
    const float* __restrict__ bias,
    float* __restrict__ C, int ldc)
{
    __shared__ unsigned short As[128][32];
    __shared__ unsigned short Bs[2][128][32];

    const int tid  = threadIdx.x;
    const int row0 = blockIdx.x * 128;
    const int col0 = blockIdx.y * 128;
    const int wave = tid >> 6;
    const int lane = tid & 63;
    const int wm   = (wave >> 1) * 64;
    const int wn   = (wave & 1) * 64;
    const int m16  = lane & 15;
    const int quad = lane >> 4;

    v4f acc[4][4] = {};

    for (int k0 = 0; k0 < 256; k0 += 32) {
        __syncthreads();
#pragma unroll
        for (int c = 0; c < 2; ++c) {
            const int linear = (wave * 2 + c) * 1024 + lane * 16;
            const int n   = linear >> 6;
            const int off = linear & 63;
            copy16_async((const char*)A  + ((size_t)(row0 + n) * 256 + k0) * 2 + off,
                         (char*)&As[0][0] + linear);
            copy16_async((const char*)Bh + ((size_t)(col0 + n) * 256 + k0) * 2 + off,
                         (char*)&Bs[0][0][0] + linear);
            copy16_async((const char*)Bl + ((size_t)(col0 + n) * 256 + k0) * 2 + off,
                         (char*)&Bs[1][0][0] + linear);
        }
        __syncthreads();

        v8s a[4], bh[4], bl[4];
#pragma unroll
        for (int i = 0; i < 4; ++i) {
            const int r  = wm + i * 16 + m16;
            const int ka = (quad ^ ((r >> 1) & 3)) << 3;
            a[i] = *(v8s*)&As[r][ka];
            const int n  = wn + i * 16 + m16;
            const int kb = (quad ^ ((n >> 1) & 3)) << 3;
            bh[i] = *(v8s*)&Bs[0][n][kb];
            bl[i] = *(v8s*)&Bs[1][n][kb];
        }
#pragma unroll
        for (int i = 0; i < 4; ++i)
#pragma unroll
            for (int j = 0; j < 4; ++j) {
                acc[i][j] = __builtin_amdgcn_mfma_f32_16x16x32_bf16(a[i], bh[j], acc[i][j], 0, 0, 0);
                acc[i][j] = __builtin_amdgcn_mfma_f32_16x16x32_bf16(a[i], bl[j], acc[i][j], 0, 0, 0);
            }
    }

#pragma unroll
    for (int j = 0; j < 4; ++j) {
        const int cl = col0 + wn + j * 16 + m16;
        const float bb = bias[cl];
#pragma unroll
        for (int i = 0; i < 4; ++i)
#pragma unroll
            for (int r = 0; r < 4; ++r) {
                const int R = row0 + wm + i * 16 + quad * 4 + r;
                C[(size_t)R * ldc + cl] = acc[i][j][r] + bb;
            }
    }
}

// ---------------------------------------------------------------------------
// Sampler: softmax(16) fused + bilinear gather from bf16 val + weighted sum.
// Thread = (bq, h, d8); 4 lanes with the same (bq,h) read one contiguous 64B
// line per corner. Output pre is bf16 with the GEMM octet swizzle baked in.
// ---------------------------------------------------------------------------
__global__ __launch_bounds__(256) void sample_kernel(
    const float* __restrict__ refp,
    const float* __restrict__ offattn,            // [9600][384]
    const unsigned short* __restrict__ val,       // [b][h][V][32] bf16
    unsigned short* __restrict__ pre)             // [9600][256] bf16 swizzled
{
    const int t  = blockIdx.x * 256 + threadIdx.x;  // 0 .. 307199
    const int d8 = t & 3;
    const int h  = (t >> 2) & 7;
    const int bq = t >> 5;
    const int b  = bq / NQ;

    const float* rp = refp + (size_t)bq * 8;
    const float* op = offattn + (size_t)bq * 384 + h * 32;
    const float* ap = offattn + (size_t)bq * 384 + 256 + h * 16;

    float aw[16];
    float m = -1e30f;
#pragma unroll
    for (int i = 0; i < 16; ++i) { aw[i] = ap[i]; m = fmaxf(m, aw[i]); }
    float s = 0.f;
#pragma unroll
    for (int i = 0; i < 16; ++i) { aw[i] = __expf(aw[i] - m); s += aw[i]; }
    const float inv = 1.f / s;
#pragma unroll
    for (int i = 0; i < 16; ++i) aw[i] *= inv;

    const int Hs[4] = {80, 40, 20, 10};
    const int St[4] = {0, 6400, 8000, 8400};

    float acc[8] = {};
#pragma unroll
    for (int l = 0; l < NL; ++l) {
        const int Wl = Hs[l], Hl = Hs[l];
        const float fW = (float)Wl, fH = (float)Hl;
        const float rx = rp[l * 2 + 0];
        const float ry = rp[l * 2 + 1];
        const unsigned short* vb =
            val + (((size_t)(b * NH + h)) * V_TOT + St[l]) * HD + d8 * 8;
#pragma unroll
        for (int p = 0; p < NP; ++p) {
            const float ox = op[l * 8 + p * 2 + 0];
            const float oy = op[l * 8 + p * 2 + 1];
            const float w  = aw[l * 4 + p];
            const float x = fmaf(rx, fW, ox) - 0.5f;
            const float y = fmaf(ry, fH, oy) - 0.5f;
            const float x0f = floorf(x), y0f = floorf(y);
            const int   x0 = (int)x0f,  y0 = (int)y0f;
            const float wx1 = x - x0f,  wy1 = y - y0f;
            const float wx0 = 1.f - wx1, wy0 = 1.f - wy1;
#pragma unroll
            for (int cy = 0; cy < 2; ++cy) {
#pragma unroll
                for (int cx = 0; cx < 2; ++cx) {
                    const int xi = x0 + cx;
                    const int yi = y0 + cy;
                    float cw = (cx ? wx1 : wx0) * (cy ? wy1 : wy0) * w;
                    const bool valid = (xi >= 0) && (xi < Wl) && (yi >= 0) && (yi < Hl);
                    cw = valid ? cw : 0.f;
                    const int xc = xi < 0 ? 0 : (xi > Wl - 1 ? Wl - 1 : xi);
                    const int yc = yi < 0 ? 0 : (yi > Hl - 1 ? Hl - 1 : yi);
                    const uint4 g = *(const uint4*)(vb + (size_t)(yc * Wl + xc) * HD);
                    const unsigned gu[4] = {g.x, g.y, g.z, g.w};
#pragma unroll
                    for (int e = 0; e < 4; ++e) {
                        acc[2*e]   = fmaf(cw, __uint_as_float(gu[e] << 16),        acc[2*e]);
                        acc[2*e+1] = fmaf(cw, __uint_as_float(gu[e] & 0xffff0000u), acc[2*e+1]);
                    }
                }
            }
        }
    }

    unsigned o[4];
#pragma unroll
    for (int e = 0; e < 4; ++e)
        o[e] = (unsigned)f2bf_rne(acc[2*e]) | ((unsigned)f2bf_rne(acc[2*e+1]) << 16);
    const int octswz = d8 ^ ((bq >> 1) & 3);
    *(uint4*)(pre + (size_t)bq * 256 + h * 32 + octswz * 8) =
        make_uint4(o[0], o[1], o[2], o[3]);
}

// ---------------------------------------------------------------------------
extern "C" void kernel_launch(void* const* d_in, const int* in_sizes, int n_in,
                              void* d_out, int out_size, void* d_ws, size_t ws_size,
                              hipStream_t stream)
{
    const float* query  = (const float*)d_in[0];
    const float* refp   = (const float*)d_in[1];
    const float* value  = (const float*)d_in[2];
    const float* W_off  = (const float*)d_in[5];
    const float* b_off  = (const float*)d_in[6];
    const float* W_attn = (const float*)d_in[7];
    const float* b_attn = (const float*)d_in[8];
    const float* W_val  = (const float*)d_in[9];
    const float* b_val  = (const float*)d_in[10];
    const float* W_out  = (const float*)d_in[11];
    const float* b_out  = (const float*)d_in[12];
    float* out = (float*)d_out;

    char* ws = (char*)d_ws;
    unsigned short* val     = (unsigned short*)ws;                       // 139,264,000 B
    float*          offattn = (float*)(ws + 139264000);                  // 14,745,600 B
    unsigned short* pre     = (unsigned short*)(ws + 154009600);         //  4,915,200 B
    unsigned short* Bval_h  = (unsigned short*)(ws + 158924800);
    unsigned short* Bval_l  = Bval_h + 65536;
    unsigned short* Boa_h   = Bval_l + 65536;
    unsigned short* Boa_l   = Boa_h + 98304;
    unsigned short* Bout_h  = Boa_l + 98304;
    unsigned short* Bout_l  = Bout_h + 65536;
    float*          b_oa    = (float*)(Bout_l + 65536);

    const dim3 blk(256);

    // 0) weight prep
    prep_weights<<<dim3(898), blk, 0, stream>>>(
        W_val, W_off, W_attn, W_out, b_off, b_attn,
        Bval_h, Bval_l, Boa_h, Boa_l, Bout_h, Bout_l, b_oa);

    // 1) val = value @ W_val + b_val -> bf16 [b][h][V][hd]   (BN=256)
    gemm_val256<<<dim3(MVAL / 128), blk, 0, stream>>>(
        value, Bval_h, Bval_l, b_val, val);

    // 2) fused off+attn projection -> f32 [9600][384]
    gemm_a32<<<dim3(BQ_TOT / 128, 3), blk, 0, stream>>>(
        query, Boa_h, Boa_l, b_oa, offattn, NOA);

    // 3) softmax + bilinear sampling + weighted sum -> pre bf16 (swizzled)
    sample_kernel<<<dim3((BQ_TOT * 32) / 256), blk, 0, stream>>>(
        refp, offattn, val, pre);

    // 4) out = pre @ W_out + b_out -> f32 [9600][256]
    gemm_a16<<<dim3(BQ_TOT / 128, 2), blk, 0, stream>>>(
        pre, Bout_h, Bout_l, b_out, out, 256);
}